// Round 3
// baseline (244.258 us; speedup 1.0000x reference)
//
#include <hip/hip_runtime.h>
#include <math.h>

// Single-head causal attention, MFMA bf16 pipeline (R3: latency-hiding rebuild).
//   x:[8,2048,1024] f32, Wq/Wk/Wv:[1024,64] f32, zero_mask:[8,2048] i32
//   out:[8,2048,64] f32
// wcvt: Wt[192][1024] bf16 (B-operand layout)
// qkv : 512 blocks x 4 waves, W in LDS per 128-K chunk (16 barriers total),
//       X streamed global->reg->bf16. Outputs: Q (pre-scaled) / K row-major,
//       V transposed into 64x64 tiles [b][kb][h][key] via LDS transpose.
// attn: grid (8,64) remapped, 2-wave blocks, double-buffered K/V LDS,
//       next-tile loads overlap compute; mask only on the diagonal tile.
//
// MFMA 16x16x32 layouts (HW-verified):
//   A[m][k]: m = lane&15, k = (lane>>4)*8 + j
//   B[k][n]: n = lane&15, k = (lane>>4)*8 + j
//   C/D:     col = lane&15, row = (lane>>4)*4 + reg

#define B_ 8
#define C_ 2048
#define E_ 1024
#define H_ 64
#define SCALE 0.02209708691207961f  // 2048^-0.5

typedef __attribute__((ext_vector_type(8))) short short8;
typedef __attribute__((ext_vector_type(4))) float floatx4;

union BF8 { short8 s8; unsigned int u[4]; uint4 u4; };

static __device__ __forceinline__ unsigned int pack_bf2(float lo, float hi) {
    unsigned int a = __builtin_bit_cast(unsigned int, lo);
    unsigned int b = __builtin_bit_cast(unsigned int, hi);
    return (a >> 16) | (b & 0xFFFF0000u);
}
static __device__ __forceinline__ unsigned short f2bf(float f) {
    return (unsigned short)(__builtin_bit_cast(unsigned int, f) >> 16);
}

// ---------------------------------------------------------------------------
// Wt[n=192][k=1024] bf16 from Wq/Wk/Wv[k][64] f32. 48 blocks.
// ---------------------------------------------------------------------------
__global__ __launch_bounds__(256) void wcvt_kernel(
    const float* __restrict__ Wq, const float* __restrict__ Wk,
    const float* __restrict__ Wv, unsigned short* __restrict__ wt)
{
    __shared__ float lds[64][68];
    const int bid = (int)blockIdx.x;
    const int m = bid >> 4, kt = bid & 15, k0 = kt * 64;
    const float* W = (m == 0) ? Wq : (m == 1) ? Wk : Wv;
    const int t = (int)threadIdx.x;
#pragma unroll
    for (int j = 0; j < 4; j++) {
        int idx4 = j * 256 + t;
        int row = idx4 >> 4, c4 = idx4 & 15;
        float4 v = *(const float4*)(W + (size_t)(k0 + row) * 64 + c4 * 4);
        *(float4*)&lds[row][c4 * 4] = v;
    }
    __syncthreads();
#pragma unroll
    for (int j = 0; j < 2; j++) {
        int g = j * 256 + t;
        int n = g >> 3, kk = (g & 7) * 8;
        unsigned int o[4];
#pragma unroll
        for (int i = 0; i < 4; i++)
            o[i] = pack_bf2(lds[kk + 2 * i][n], lds[kk + 2 * i + 1][n]);
        *(uint4*)(wt + (size_t)(m * 64 + n) * 1024 + k0 + kk) =
            make_uint4(o[0], o[1], o[2], o[3]);
    }
}

// ---------------------------------------------------------------------------
// QKV: M=16384, N=192, K=1024. 512 blocks x 256 thr.
// Wave w: rows r0+(w>>1)*16, cols (w&1)*96 (6 n-tiles). 8 waves/CU.
// ---------------------------------------------------------------------------
__global__ __launch_bounds__(256, 2) void qkv_kernel(
    const float* __restrict__ X, const unsigned short* __restrict__ wt,
    unsigned short* __restrict__ qg, unsigned short* __restrict__ kg,
    unsigned short* __restrict__ vtile)
{
    __shared__ unsigned short wlds[192 * 136];   // [n][128k + 8 pad] = 52 KB
    __shared__ unsigned short vstage[64 * 40];   // [h][32key + 8 pad]

    const int t = (int)threadIdx.x;
    const int w = t >> 6, lane = t & 63;
    const int l15 = lane & 15, quad = lane >> 4;
    const int r0 = (int)blockIdx.x * 32;
    const int mrow = r0 + (w >> 1) * 16 + l15;   // this lane's A row
    const int ncol0 = (w & 1) * 96;

    floatx4 acc[6];
#pragma unroll
    for (int j = 0; j < 6; j++) acc[j] = (floatx4){0.f, 0.f, 0.f, 0.f};

    for (int c = 0; c < 8; c++) {
        const int k0 = c * 128;
        // stage W chunk 192x128 (3072 16B-granules, 12/thread)
        uint4 wreg[12];
#pragma unroll
        for (int j = 0; j < 12; j++) {
            int g = j * 256 + t;
            int n = g >> 4, kk = (g & 15) * 8;
            wreg[j] = *(const uint4*)(wt + (size_t)n * 1024 + k0 + kk);
        }
        __syncthreads();
#pragma unroll
        for (int j = 0; j < 12; j++) {
            int g = j * 256 + t;
            int n = g >> 4, kk = (g & 15) * 8;
            *(uint4*)&wlds[n * 136 + kk] = wreg[j];
        }
        __syncthreads();

#pragma unroll
        for (int ks = 0; ks < 4; ks++) {
            const float* xp = X + (size_t)mrow * E_ + k0 + ks * 32 + quad * 8;
            float4 x0 = *(const float4*)xp;
            float4 x1 = *(const float4*)(xp + 4);
            BF8 a;
            a.u[0] = pack_bf2(x0.x, x0.y);
            a.u[1] = pack_bf2(x0.z, x0.w);
            a.u[2] = pack_bf2(x1.x, x1.y);
            a.u[3] = pack_bf2(x1.z, x1.w);
#pragma unroll
            for (int nt = 0; nt < 6; nt++) {
                short8 bfr = *(const short8*)&wlds[(ncol0 + nt * 16 + l15) * 136
                                                  + ks * 32 + quad * 8];
                acc[nt] = __builtin_amdgcn_mfma_f32_16x16x32_bf16(
                    a.s8, bfr, acc[nt], 0, 0, 0);
            }
        }
    }

    // epilogue: C row = (w>>1)*16 + quad*4 + r, col = ncol0 + nt*16 + l15
    const int bb = r0 >> 11;
    const int keybase = r0 & 2047;
    const int rowl0 = (w >> 1) * 16 + quad * 4;
#pragma unroll
    for (int nt = 0; nt < 6; nt++) {
        const int n = ncol0 + nt * 16 + l15;
        if (n < 64) {            // Q, pre-scaled
#pragma unroll
            for (int r = 0; r < 4; r++)
                qg[(size_t)(r0 + rowl0 + r) * 64 + n] = f2bf(acc[nt][r] * SCALE);
        } else if (n < 128) {    // K
#pragma unroll
            for (int r = 0; r < 4; r++)
                kg[(size_t)(r0 + rowl0 + r) * 64 + (n - 64)] = f2bf(acc[nt][r]);
        } else {                 // V -> LDS transpose stage
            const int h = n - 128;
            unsigned int p0 = pack_bf2(acc[nt][0], acc[nt][1]);
            unsigned int p1 = pack_bf2(acc[nt][2], acc[nt][3]);
            *(unsigned int*)&vstage[h * 40 + rowl0] = p0;
            *(unsigned int*)&vstage[h * 40 + rowl0 + 2] = p1;
        }
    }
    __syncthreads();
    // V tile store: 64 h x 32 keys -> vtile[b][kb][h][64], 64B full sectors
    {
        const int h = t >> 2, part = t & 3;
        uint4 v = *(const uint4*)&vstage[h * 40 + part * 8];
        *(uint4*)(vtile + ((size_t)(bb * 32 + (keybase >> 6)) * 64 + h) * 64
                  + (keybase & 63) + part * 8) = v;
    }
}

// ---------------------------------------------------------------------------
// Attention: grid (8, 64) remapped; 128 thr (2 waves); 32 q-rows/block.
// Double-buffered K/V LDS; next-tile global loads overlap compute.
// ---------------------------------------------------------------------------
__global__ __launch_bounds__(128, 2) void attn_kernel(
    const unsigned short* __restrict__ qg, const unsigned short* __restrict__ kg,
    const unsigned short* __restrict__ vtile, const int* __restrict__ zmask,
    float* __restrict__ out)
{
    __shared__ unsigned short Klds[2][64 * 72];  // [key][64h + 8 pad]
    __shared__ unsigned short Vlds[2][64 * 72];  // [h][64key + 8 pad]
    __shared__ unsigned short Ps[2 * 16 * 88];   // per-wave P [q16][64key + 24 pad]

    const int t = (int)threadIdx.x;
    const int w = t >> 6, lane = t & 63;
    const int l15 = lane & 15, quad = lane >> 4;
    const int b = (int)blockIdx.x;
    const int y = (int)blockIdx.y;
    const int qt = (y < 32) ? y : (95 - y);      // causal load-balance remap
    const int q0 = qt * 32;
    const int qlo = q0 + w * 16;
    const int myrow = qlo + quad * 4;

    short8 qfr[2];
#pragma unroll
    for (int kc = 0; kc < 2; kc++)
        qfr[kc] = *(const short8*)(qg + ((size_t)b * C_ + qlo + l15) * 64
                                   + kc * 32 + quad * 8);

    floatx4 accO[4];
#pragma unroll
    for (int i = 0; i < 4; i++) accO[i] = (floatx4){0.f, 0.f, 0.f, 0.f};
    float lsum[4] = {0.f, 0.f, 0.f, 0.f};

    const int nfull = q0 >> 6;     // unmasked tiles; tile nfull is the masked one
    const int nkt = nfull + 1;

    uint4 kreg[4], vreg[4];
    // preload tile 0
#pragma unroll
    for (int j = 0; j < 4; j++) {
        int g = j * 128 + t;
        int row = g >> 3, gk = (g & 7) * 8;
        kreg[j] = *(const uint4*)(kg + ((size_t)b * C_ + row) * 64 + gk);
        vreg[j] = *(const uint4*)(vtile + ((size_t)(b * 32 + 0) * 64 + row) * 64 + gk);
    }

    for (int kt = 0; kt < nkt; kt++) {
        const int buf = kt & 1;
#pragma unroll
        for (int j = 0; j < 4; j++) {
            int g = j * 128 + t;
            int row = g >> 3, gk = (g & 7) * 8;
            *(uint4*)&Klds[buf][row * 72 + gk] = kreg[j];
            *(uint4*)&Vlds[buf][row * 72 + gk] = vreg[j];
        }
        __syncthreads();
        if (kt + 1 < nkt) {      // overlap next tile's loads with compute
            const int k0n = (kt + 1) * 64;
#pragma unroll
            for (int j = 0; j < 4; j++) {
                int g = j * 128 + t;
                int row = g >> 3, gk = (g & 7) * 8;
                kreg[j] = *(const uint4*)(kg + ((size_t)b * C_ + k0n + row) * 64 + gk);
                vreg[j] = *(const uint4*)(vtile
                            + ((size_t)(b * 32 + kt + 1) * 64 + row) * 64 + gk);
            }
        }

        // S = Q K^T
        floatx4 s[4];
#pragma unroll
        for (int nt = 0; nt < 4; nt++) {
            short8 kf0 = *(const short8*)&Klds[buf][(nt * 16 + l15) * 72 + quad * 8];
            short8 kf1 = *(const short8*)&Klds[buf][(nt * 16 + l15) * 72 + 32 + quad * 8];
            floatx4 z = (floatx4){0.f, 0.f, 0.f, 0.f};
            z = __builtin_amdgcn_mfma_f32_16x16x32_bf16(qfr[0], kf0, z, 0, 0, 0);
            s[nt] = __builtin_amdgcn_mfma_f32_16x16x32_bf16(qfr[1], kf1, z, 0, 0, 0);
        }
        // P = exp(s); causal mask only on the diagonal tile
        float pr[4][4];
#pragma unroll
        for (int nt = 0; nt < 4; nt++)
#pragma unroll
            for (int r = 0; r < 4; r++) pr[nt][r] = __expf(s[nt][r]);
        if (kt == nfull) {
            const int k0 = kt * 64;
#pragma unroll
            for (int nt = 0; nt < 4; nt++) {
                const int key = k0 + nt * 16 + l15;
#pragma unroll
                for (int r = 0; r < 4; r++)
                    if (key > myrow + r) pr[nt][r] = 0.f;
            }
        }
#pragma unroll
        for (int nt = 0; nt < 4; nt++)
#pragma unroll
            for (int r = 0; r < 4; r++) {
                lsum[r] += pr[nt][r];
                Ps[(w * 16 + quad * 4 + r) * 88 + nt * 16 + l15] = f2bf(pr[nt][r]);
            }
        // O += P V  (P: C-layout -> A via per-wave LDS; V^T already B-layout)
#pragma unroll
        for (int kc = 0; kc < 2; kc++) {
            short8 af = *(const short8*)&Ps[(w * 16 + l15) * 88 + kc * 32 + quad * 8];
#pragma unroll
            for (int nt = 0; nt < 4; nt++) {
                short8 vf = *(const short8*)&Vlds[buf][(nt * 16 + l15) * 72
                                                       + kc * 32 + quad * 8];
                accO[nt] = __builtin_amdgcn_mfma_f32_16x16x32_bf16(
                    af, vf, accO[nt], 0, 0, 0);
            }
        }
    }

    // row sums over the 16 col-lanes
#pragma unroll
    for (int r = 0; r < 4; r++) {
        float v = lsum[r];
        v += __shfl_xor(v, 1);
        v += __shfl_xor(v, 2);
        v += __shfl_xor(v, 4);
        v += __shfl_xor(v, 8);
        lsum[r] = v;
    }
    float inv[4];
#pragma unroll
    for (int r = 0; r < 4; r++) {
        int zm = zmask[b * C_ + myrow + r];
        inv[r] = zm ? 0.f : 1.0f / lsum[r];
    }
#pragma unroll
    for (int nt = 0; nt < 4; nt++)
#pragma unroll
        for (int r = 0; r < 4; r++)
            out[(size_t)(b * C_ + myrow + r) * 64 + nt * 16 + l15] =
                accO[nt][r] * inv[r];
}

// ---------------------------------------------------------------------------
extern "C" void kernel_launch(void* const* d_in, const int* in_sizes, int n_in,
                              void* d_out, int out_size, void* d_ws, size_t ws_size,
                              hipStream_t stream) {
    const float* X  = (const float*)d_in[0];
    const float* Wq = (const float*)d_in[1];
    const float* Wk = (const float*)d_in[2];
    const float* Wv = (const float*)d_in[3];
    const int*   zm = (const int*)d_in[4];
    float* out = (float*)d_out;

    unsigned short* qg    = (unsigned short*)d_ws;               // 2 MB
    unsigned short* kg    = qg    + (size_t)B_ * C_ * H_;        // 2 MB
    unsigned short* vtile = kg    + (size_t)B_ * C_ * H_;        // 2 MB, [b][kb][h][64]
    unsigned short* wt    = vtile + (size_t)B_ * C_ * H_;        // 384 KB

    wcvt_kernel<<<dim3(48), dim3(256), 0, stream>>>(Wq, Wk, Wv, wt);
    qkv_kernel<<<dim3(512), dim3(256), 0, stream>>>(X, wt, qg, kg, vtile);
    attn_kernel<<<dim3(B_, 64), dim3(128), 0, stream>>>(qg, kg, vtile, zm, out);
}

// Round 5
// 147.951 us; speedup vs baseline: 1.6509x; 1.6509x over previous
//
#include <hip/hip_runtime.h>
#include <math.h>

// Single-head causal attention, MFMA bf16 pipeline (R5 = R4 + crash fixes).
//   x:[8,2048,1024] f32, Wq/Wk/Wv:[1024,64] f32, zero_mask:[8,2048] i32
//   out:[8,2048,64] f32
// wcvt: Wt[192][1024] bf16 (B-operand layout)
// qkv : 512 blocks x 4 waves; W chunks staged via async global_load_lds
//       (XOR-swizzled source so unpadded LDS rows are conflict-free),
//       double-buffered; X global->reg->bf16.
// attn: split-K flash (softmax w/o max subtraction is LINEAR in keys).
//       grid (8,64,2): z=0 tiles [0,16), z=1 tiles [16,nkt).
//       qt<32  -> z=0 covers everything, normalizes + zmask, writes out.
//       qt>=32 -> both z write unnormalized (O,l) partials for rows>=1024.
// comb: sums the two partials for rows>=1024, normalizes, applies zmask.
//
// MFMA 16x16x32 layouts (HW-verified):
//   A[m][k]: m = lane&15, k = (lane>>4)*8 + j
//   B[k][n]: n = lane&15, k = (lane>>4)*8 + j
//   C/D:     col = lane&15, row = (lane>>4)*4 + reg
//
// Swizzle: row of 64 bf16 = 8 granules of 16B; granule g of row r is stored
// at slot g^(r&7). global_load_lds needs lane-linear LDS dest, so the
// permutation is applied to the per-lane GLOBAL source address; readers
// apply the same XOR.

#define B_ 8
#define C_ 2048
#define E_ 1024
#define H_ 64
#define SCALE 0.02209708691207961f  // 2048^-0.5

typedef __attribute__((ext_vector_type(8))) short short8;
typedef __attribute__((ext_vector_type(4))) float floatx4;

union BF8 { short8 s8; unsigned int u[4]; };

static __device__ __forceinline__ unsigned int pack_bf2(float lo, float hi) {
    unsigned int a = __builtin_bit_cast(unsigned int, lo);
    unsigned int b = __builtin_bit_cast(unsigned int, hi);
    return (a >> 16) | (b & 0xFFFF0000u);
}
static __device__ __forceinline__ unsigned short f2bf(float f) {
    return (unsigned short)(__builtin_bit_cast(unsigned int, f) >> 16);
}
static __device__ __forceinline__ void load_lds16(const void* g, void* l) {
    __builtin_amdgcn_global_load_lds(
        (const __attribute__((address_space(1))) void*)g,
        (__attribute__((address_space(3))) void*)l, 16, 0, 0);
}

// ---------------------------------------------------------------------------
// Wt[n=192][k=1024] bf16 from Wq/Wk/Wv[k][64] f32. 48 blocks.
// ---------------------------------------------------------------------------
__global__ __launch_bounds__(256) void wcvt_kernel(
    const float* __restrict__ Wq, const float* __restrict__ Wk,
    const float* __restrict__ Wv, unsigned short* __restrict__ wt)
{
    __shared__ float lds[64][68];
    const int bid = (int)blockIdx.x;
    const int m = bid >> 4, kt = bid & 15, k0 = kt * 64;
    const float* W = (m == 0) ? Wq : (m == 1) ? Wk : Wv;
    const int t = (int)threadIdx.x;
#pragma unroll
    for (int j = 0; j < 4; j++) {
        int idx4 = j * 256 + t;
        int row = idx4 >> 4, c4 = idx4 & 15;
        float4 v = *(const float4*)(W + (size_t)(k0 + row) * 64 + c4 * 4);
        *(float4*)&lds[row][c4 * 4] = v;
    }
    __syncthreads();
#pragma unroll
    for (int j = 0; j < 2; j++) {
        int g = j * 256 + t;
        int n = g >> 3, kk = (g & 7) * 8;
        unsigned int o[4];
#pragma unroll
        for (int i = 0; i < 4; i++)
            o[i] = pack_bf2(lds[kk + 2 * i][n], lds[kk + 2 * i + 1][n]);
        *(uint4*)(wt + (size_t)(m * 64 + n) * 1024 + k0 + kk) =
            make_uint4(o[0], o[1], o[2], o[3]);
    }
}

// ---------------------------------------------------------------------------
// QKV: M=16384, N=192, K=1024. 512 blocks x 256 thr, 32 rows/block.
// ---------------------------------------------------------------------------
__global__ __launch_bounds__(256, 2) void qkv_kernel(
    const float* __restrict__ X, const unsigned short* __restrict__ wt,
    unsigned short* __restrict__ qg, unsigned short* __restrict__ kg,
    unsigned short* __restrict__ vtile)
{
    __shared__ unsigned short wlds[2][192 * 64];   // 2 x 24 KB, swizzled rows
    __shared__ unsigned short vstage[64 * 40];     // [h][32key + 8 pad]

    const int t = (int)threadIdx.x;
    const int w = t >> 6, lane = t & 63;
    const int l15 = lane & 15, quad = lane >> 4;
    const int r0 = (int)blockIdx.x * 32;
    const int mrow = r0 + (w >> 1) * 16 + l15;
    const int ncol0 = (w & 1) * 96;

    const int srow_off = lane >> 3;        // row within 8-row region
    const int sgs = lane & 7;              // stored granule slot

    floatx4 acc[6];
#pragma unroll
    for (int j = 0; j < 6; j++) acc[j] = (floatx4){0.f, 0.f, 0.f, 0.f};

    // stage chunk 0 into buf 0
#pragma unroll
    for (int j = 0; j < 6; j++) {
        const int region = w * 6 + j;
        const int row = region * 8 + srow_off;
        const int gsrc = sgs ^ (row & 7);
        load_lds16(wt + (size_t)row * 1024 + gsrc * 8, &wlds[0][region * 512]);
    }
    float4 xr[4];
#pragma unroll
    for (int kc = 0; kc < 2; kc++) {
        const float* xp = X + (size_t)mrow * E_ + kc * 32 + quad * 8;
        xr[kc * 2]     = *(const float4*)xp;
        xr[kc * 2 + 1] = *(const float4*)(xp + 4);
    }

    int buf = 0;
    for (int c = 0; c < 16; c++) {
        __syncthreads();   // barrier drains vmcnt: stage c + X c complete
        float4 xr2[4];
        if (c < 15) {
            const int k0n = (c + 1) * 64;
#pragma unroll
            for (int kc = 0; kc < 2; kc++) {
                const float* xp = X + (size_t)mrow * E_ + k0n + kc * 32 + quad * 8;
                xr2[kc * 2]     = *(const float4*)xp;
                xr2[kc * 2 + 1] = *(const float4*)(xp + 4);
            }
#pragma unroll
            for (int j = 0; j < 6; j++) {
                const int region = w * 6 + j;
                const int row = region * 8 + srow_off;
                const int gsrc = sgs ^ (row & 7);
                load_lds16(wt + (size_t)row * 1024 + k0n + gsrc * 8,
                           &wlds[buf ^ 1][region * 512]);
            }
        }
#pragma unroll
        for (int kc = 0; kc < 2; kc++) {
            BF8 a;
            float4 f0 = xr[kc * 2], f1 = xr[kc * 2 + 1];
            a.u[0] = pack_bf2(f0.x, f0.y);
            a.u[1] = pack_bf2(f0.z, f0.w);
            a.u[2] = pack_bf2(f1.x, f1.y);
            a.u[3] = pack_bf2(f1.z, f1.w);
#pragma unroll
            for (int nt = 0; nt < 6; nt++) {
                const int n = ncol0 + nt * 16 + l15;
                const int g = kc * 4 + quad;
                short8 bfr = *(const short8*)&wlds[buf][n * 64 + (g ^ (n & 7)) * 8];
                acc[nt] = __builtin_amdgcn_mfma_f32_16x16x32_bf16(
                    a.s8, bfr, acc[nt], 0, 0, 0);
            }
        }
#pragma unroll
        for (int j = 0; j < 4; j++) xr[j] = xr2[j];
        buf ^= 1;
    }

    // epilogue
    const int bb = r0 >> 11;
    const int keybase = r0 & 2047;
    const int rowl0 = (w >> 1) * 16 + quad * 4;
#pragma unroll
    for (int nt = 0; nt < 6; nt++) {
        const int n = ncol0 + nt * 16 + l15;
        if (n < 64) {
#pragma unroll
            for (int r = 0; r < 4; r++)
                qg[(size_t)(r0 + rowl0 + r) * 64 + n] = f2bf(acc[nt][r] * SCALE);
        } else if (n < 128) {
#pragma unroll
            for (int r = 0; r < 4; r++)
                kg[(size_t)(r0 + rowl0 + r) * 64 + (n - 64)] = f2bf(acc[nt][r]);
        } else {
            const int h = n - 128;
            unsigned int p0 = pack_bf2(acc[nt][0], acc[nt][1]);
            unsigned int p1 = pack_bf2(acc[nt][2], acc[nt][3]);
            *(unsigned int*)&vstage[h * 40 + rowl0] = p0;
            *(unsigned int*)&vstage[h * 40 + rowl0 + 2] = p1;
        }
    }
    __syncthreads();
    {   // V tile: 64 h x 32 keys -> vtile[b][kb][h][64key]
        const int h = t >> 2, part = t & 3;
        uint4 v = *(const uint4*)&vstage[h * 40 + part * 8];
        *(uint4*)(vtile + ((size_t)(bb * 32 + (keybase >> 6)) * 64 + h) * 64
                  + (keybase & 63) + part * 8) = v;
    }
}

// ---------------------------------------------------------------------------
// Attention split-K. Grid (8, 64, 2); 128 thr (2 waves); 32 q-rows/block.
// qt<32: z=0 does all tiles, writes normalized out (zmask applied).
// qt>=32: z in {0,1} write unnormalized partials for local rows myrow-1024.
// ---------------------------------------------------------------------------
__global__ __launch_bounds__(128, 2) void attn_kernel(
    const unsigned short* __restrict__ qg, const unsigned short* __restrict__ kg,
    const unsigned short* __restrict__ vtile, const int* __restrict__ zmask,
    float* __restrict__ opart, float* __restrict__ lpart,
    float* __restrict__ out)
{
    __shared__ unsigned short Klds[2][64 * 64];  // swizzled [key][64h]
    __shared__ unsigned short Vlds[2][64 * 64];  // swizzled [h][64key]
    __shared__ unsigned short Ps[2 * 16 * 88];

    const int t = (int)threadIdx.x;
    const int w = t >> 6, lane = t & 63;
    const int l15 = lane & 15, quad = lane >> 4;
    const int b = (int)blockIdx.x;
    const int qt = (int)blockIdx.y;
    const int z = (int)blockIdx.z;
    const int q0 = qt * 32;
    const int nkt = (q0 >> 6) + 1;
    const int t0 = z * 16;
    const int t1 = (z == 0) ? ((nkt < 16) ? nkt : 16) : nkt;
    if (t0 >= t1) return;     // z=1 with qt<32: nothing to do

    const int qlo = q0 + w * 16;
    const int myrow = qlo + quad * 4;
    const int srow_off = lane >> 3, sgs = lane & 7;

    short8 qfr[2];
#pragma unroll
    for (int kc = 0; kc < 2; kc++)
        qfr[kc] = *(const short8*)(qg + ((size_t)b * C_ + qlo + l15) * 64
                                   + kc * 32 + quad * 8);

    floatx4 accO[4];
#pragma unroll
    for (int i = 0; i < 4; i++) accO[i] = (floatx4){0.f, 0.f, 0.f, 0.f};
    float lsum[4] = {0.f, 0.f, 0.f, 0.f};

    // stage tile t0 into buf 0
#pragma unroll
    for (int j = 0; j < 4; j++) {
        const int region = w * 4 + j;
        const int row = region * 8 + srow_off;
        const int gsrc = sgs ^ (row & 7);
        load_lds16(kg + ((size_t)b * C_ + t0 * 64 + row) * 64 + gsrc * 8,
                   &Klds[0][region * 512]);
        load_lds16(vtile + (((size_t)b * 32 + t0) * 64 + row) * 64 + gsrc * 8,
                   &Vlds[0][region * 512]);
    }

    int buf = 0;
    for (int kt = t0; kt < t1; kt++) {
        __syncthreads();
        if (kt + 1 < t1) {
            const int k0n = (kt + 1) * 64;
#pragma unroll
            for (int j = 0; j < 4; j++) {
                const int region = w * 4 + j;
                const int row = region * 8 + srow_off;
                const int gsrc = sgs ^ (row & 7);
                load_lds16(kg + ((size_t)b * C_ + k0n + row) * 64 + gsrc * 8,
                           &Klds[buf ^ 1][region * 512]);
                load_lds16(vtile + (((size_t)b * 32 + kt + 1) * 64 + row) * 64 + gsrc * 8,
                           &Vlds[buf ^ 1][region * 512]);
            }
        }

        floatx4 s[4];
#pragma unroll
        for (int nt = 0; nt < 4; nt++) {
            const int row = nt * 16 + l15;
            short8 kf0 = *(const short8*)&Klds[buf][row * 64 + ((quad) ^ (row & 7)) * 8];
            short8 kf1 = *(const short8*)&Klds[buf][row * 64 + ((4 + quad) ^ (row & 7)) * 8];
            floatx4 zz = (floatx4){0.f, 0.f, 0.f, 0.f};
            zz = __builtin_amdgcn_mfma_f32_16x16x32_bf16(qfr[0], kf0, zz, 0, 0, 0);
            s[nt] = __builtin_amdgcn_mfma_f32_16x16x32_bf16(qfr[1], kf1, zz, 0, 0, 0);
        }
        float pr[4][4];
#pragma unroll
        for (int nt = 0; nt < 4; nt++)
#pragma unroll
            for (int r = 0; r < 4; r++) pr[nt][r] = __expf(s[nt][r]);
        if (kt == nkt - 1) {   // diagonal tile: causal mask
            const int k0 = kt * 64;
#pragma unroll
            for (int nt = 0; nt < 4; nt++) {
                const int key = k0 + nt * 16 + l15;
#pragma unroll
                for (int r = 0; r < 4; r++)
                    if (key > myrow + r) pr[nt][r] = 0.f;
            }
        }
#pragma unroll
        for (int nt = 0; nt < 4; nt++)
#pragma unroll
            for (int r = 0; r < 4; r++) {
                lsum[r] += pr[nt][r];
                Ps[(w * 16 + quad * 4 + r) * 88 + nt * 16 + l15] = f2bf(pr[nt][r]);
            }
#pragma unroll
        for (int kc = 0; kc < 2; kc++) {
            short8 af = *(const short8*)&Ps[(w * 16 + l15) * 88 + kc * 32 + quad * 8];
#pragma unroll
            for (int nt = 0; nt < 4; nt++) {
                const int row = nt * 16 + l15;
                short8 vf = *(const short8*)&Vlds[buf][row * 64
                                + ((kc * 4 + quad) ^ (row & 7)) * 8];
                accO[nt] = __builtin_amdgcn_mfma_f32_16x16x32_bf16(
                    af, vf, accO[nt], 0, 0, 0);
            }
        }
        buf ^= 1;
    }

    // reduce l across the 16 col-lanes
#pragma unroll
    for (int r = 0; r < 4; r++) {
        float v = lsum[r];
        v += __shfl_xor(v, 1);
        v += __shfl_xor(v, 2);
        v += __shfl_xor(v, 4);
        v += __shfl_xor(v, 8);
        lsum[r] = v;
    }

    if (q0 < 1024) {
        // single-split rows: normalize + zmask, write final out
        float inv[4];
#pragma unroll
        for (int r = 0; r < 4; r++) {
            int zm = zmask[b * C_ + myrow + r];
            inv[r] = zm ? 0.f : 1.0f / lsum[r];
        }
#pragma unroll
        for (int nt = 0; nt < 4; nt++)
#pragma unroll
            for (int r = 0; r < 4; r++)
                out[(size_t)(b * C_ + myrow + r) * 64 + nt * 16 + l15] =
                    accO[nt][r] * inv[r];
    } else {
        // partial rows: opart[z][b][row-1024][h], lpart[z][b][row-1024]
        const int lrow = myrow - 1024;
        float* ob = opart + ((size_t)(z * 8 + b) * 1024 + lrow) * 64;
#pragma unroll
        for (int nt = 0; nt < 4; nt++)
#pragma unroll
            for (int r = 0; r < 4; r++)
                ob[(size_t)r * 64 + nt * 16 + l15] = accO[nt][r];
        if (l15 == 0) {
#pragma unroll
            for (int r = 0; r < 4; r++)
                lpart[(size_t)(z * 8 + b) * 1024 + lrow + r] = lsum[r];
        }
    }
}

// ---------------------------------------------------------------------------
// Combine rows >= 1024: out = (O0+O1)/(l0+l1), zmask applied.
// 8 b x 1024 rows x 16 float4 = 131072 threads -> 512 blocks x 256.
// ---------------------------------------------------------------------------
__global__ __launch_bounds__(256) void combine_kernel(
    const float* __restrict__ opart, const float* __restrict__ lpart,
    const int* __restrict__ zmask, float* __restrict__ out)
{
    const int gid = (int)blockIdx.x * 256 + (int)threadIdx.x;  // 0..131071
    const int b = gid >> 14;           // /16384
    const int rem = gid & 16383;
    const int lrow = rem >> 4;         // 0..1023
    const int f4 = rem & 15;

    const size_t o0 = ((size_t)(0 * 8 + b) * 1024 + lrow) * 64 + f4 * 4;
    const size_t o1 = ((size_t)(1 * 8 + b) * 1024 + lrow) * 64 + f4 * 4;
    float4 a = *(const float4*)(opart + o0);
    float4 c = *(const float4*)(opart + o1);
    float l = lpart[(size_t)(0 * 8 + b) * 1024 + lrow]
            + lpart[(size_t)(1 * 8 + b) * 1024 + lrow];
    const int row = 1024 + lrow;
    const float inv = zmask[b * C_ + row] ? 0.f : 1.0f / l;
    *(float4*)(out + (size_t)(b * C_ + row) * 64 + f4 * 4) =
        make_float4((a.x + c.x) * inv, (a.y + c.y) * inv,
                    (a.z + c.z) * inv, (a.w + c.w) * inv);
}

// ---------------------------------------------------------------------------
extern "C" void kernel_launch(void* const* d_in, const int* in_sizes, int n_in,
                              void* d_out, int out_size, void* d_ws, size_t ws_size,
                              hipStream_t stream) {
    const float* X  = (const float*)d_in[0];
    const float* Wq = (const float*)d_in[1];
    const float* Wk = (const float*)d_in[2];
    const float* Wv = (const float*)d_in[3];
    const int*   zm = (const int*)d_in[4];
    float* out = (float*)d_out;

    unsigned short* qg    = (unsigned short*)d_ws;               // 2 MB
    unsigned short* kg    = qg    + (size_t)B_ * C_ * H_;        // 2 MB
    unsigned short* vtile = kg    + (size_t)B_ * C_ * H_;        // 2 MB
    unsigned short* wt    = vtile + (size_t)B_ * C_ * H_;        // 384 KB
    float* opart = (float*)(wt + (size_t)192 * 1024);            // 4 MB
    float* lpart = opart + (size_t)2 * 8 * 1024 * 64;            // 64 KB
    // total ~10.4 MB (proven ws floor: 12 MB from R1)

    wcvt_kernel<<<dim3(48), dim3(256), 0, stream>>>(Wq, Wk, Wv, wt);
    qkv_kernel<<<dim3(512), dim3(256), 0, stream>>>(X, wt, qg, kg, vtile);
    attn_kernel<<<dim3(B_, 64, 2), dim3(128), 0, stream>>>(
        qg, kg, vtile, zm, opart, lpart, out);
    combine_kernel<<<dim3(512), dim3(256), 0, stream>>>(opart, lpart, zm, out);
}